// Round 7
// baseline (289.418 us; speedup 1.0000x reference)
//
#include <hip/hip_runtime.h>
#include <math.h>

#define NN 8192
#define DD 256
#define EPSV 1e-6f
#define BM 128
#define BN 64
#define CSPLIT 4
#define COLS_PER_BLOCK (NN / CSPLIT)  // 2048
#define NJT (COLS_PER_BLOCK / BN)     // 32
#define TSTR 266

typedef __bf16 bf16x8 __attribute__((ext_vector_type(8)));
typedef float f32x16 __attribute__((ext_vector_type(16)));
typedef unsigned short ushort;
typedef unsigned int uint;

// ws layout: Oacc[NN*DD] f32 | lacc[NN] f32 | qni[NN] float2 | qbfA[NN*DD] bf16 | qbfB[NN*DD] bf16
// qbfA (A/B frag-major, row-blocks of 64): elem(row,f) at ((rb*32 + f/8)*64 + row%64)*8 + f%8
// qbfB (PV B-frag-major, j-blocks of 64): elem(j,f)  at ((jb*8 + j%64/8)*256 + f)*8 + j%8

__device__ inline ushort f2bf(float x) {
    uint u = __float_as_uint(x);
    u += 0x7fffu + ((u >> 16) & 1u);
    return (ushort)(u >> 16);
}

__global__ void prep_kernel(const float* __restrict__ q, const float* __restrict__ cp,
                            ushort* __restrict__ qbfA, ushort* __restrict__ qbfB,
                            float2* __restrict__ qni,
                            float* __restrict__ Oacc, float* __restrict__ lacc) {
    __shared__ ushort T[64 * TSTR];
    const int t = threadIdx.x;
    const int b = blockIdx.x;
    float4 z4 = make_float4(0.f, 0.f, 0.f, 0.f);
    #pragma unroll
    for (int i = 0; i < 16; ++i) ((float4*)Oacc)[b * 4096 + i * 256 + t] = z4;
    if (t < 16) ((float4*)lacc)[b * 16 + t] = z4;

    const int pr = t >> 2, fq = t & 3;
    const int row = b * 64 + pr;
    const float4* src = (const float4*)(q + (size_t)row * DD + fq * 64);
    ushort loc[64];
    float ss = 0.f;
    #pragma unroll
    for (int i = 0; i < 16; ++i) {
        float4 v = src[i];
        ushort b0 = f2bf(v.x), b1 = f2bf(v.y), b2 = f2bf(v.z), b3 = f2bf(v.w);
        loc[i * 4 + 0] = b0; loc[i * 4 + 1] = b1; loc[i * 4 + 2] = b2; loc[i * 4 + 3] = b3;
        float r0 = __uint_as_float((uint)b0 << 16), r1 = __uint_as_float((uint)b1 << 16);
        float r2 = __uint_as_float((uint)b2 << 16), r3 = __uint_as_float((uint)b3 << 16);
        ss += r0 * r0 + r1 * r1 + r2 * r2 + r3 * r3;
    }
    // qbfA: chunk c = fq*8+k holds feats c*8..c*8+7 of row (rl=pr), row-block b
    #pragma unroll
    for (int k = 0; k < 8; ++k)
        *(uint4*)(qbfA + (((size_t)b * 32 + fq * 8 + k) * 64 + pr) * 8) = *(uint4*)&loc[k * 8];
    #pragma unroll
    for (int k = 0; k < 32; ++k)
        *(ushort2*)&T[pr * TSTR + fq * 64 + k * 2] = *(ushort2*)&loc[k * 2];
    ss += __shfl_xor(ss, 1, 64);
    ss += __shfl_xor(ss, 2, 64);
    if (fq == 0) {
        float cc = fmaxf(cp[0], EPSV);
        float tt = fmaxf(1.0f - cc * ss, EPSV);
        qni[row] = make_float2(ss, sqrtf(2.0f * cc) / tt);
    }
    __syncthreads();
    // qbfB: j-block b; slot c' = quarter*2+h holds j = quarter*16 + h*8 + {0..7} for feature f
    #pragma unroll
    for (int pass = 0; pass < 4; ++pass) {
        int f = pass * 64 + (t >> 2);
        int quarter = t & 3;
        ushort tmp[16];
        #pragma unroll
        for (int i = 0; i < 16; ++i) tmp[i] = T[(quarter * 16 + i) * TSTR + f];
        *(uint4*)(qbfB + (((size_t)b * 8 + quarter * 2 + 0) * 256 + f) * 8) = *(uint4*)&tmp[0];
        *(uint4*)(qbfB + (((size_t)b * 8 + quarter * 2 + 1) * 256 + f) * 8) = *(uint4*)&tmp[8];
    }
}

__global__ __launch_bounds__(512, 2) void flash_kernel(
    const ushort* __restrict__ qbfA, const ushort* __restrict__ qbfB,
    const float* __restrict__ cp, const float2* __restrict__ qni,
    float* __restrict__ Oacc, float* __restrict__ lacc) {
    __shared__ char px[32768];  // P-exchange: 2 buffers x 16 slots x 1KB A-frags

    const int tid = threadIdx.x;
    const int lane = tid & 63;
    const int w = tid >> 6;     // 0..7
    const int l31 = lane & 31;
    const int lhi = lane >> 5;
    const int mr = w >> 1;      // q-row range mr*32..+31
    const int jh = w & 1;       // j half (32 j), also O feat-half jh*128

    const int lid = blockIdx.x;
    const int cs = lid & 3;     // col-split pinned per XCD
    const int rb = lid >> 2;
    const int R0 = rb * BM;
    const int jbC0 = cs * (COLS_PER_BLOCK / 64);

    const float cc = fmaxf(cp[0], EPSV);
    const float nrsc = -rsqrtf(cc);

    // persistent Q B-fragments: lane n = q-row R0+mr*32+l31, k-chunks over 256 feats
    bf16x8 qa[16];
    {
        const int jbQ = (R0 >> 6) + (mr >> 1);
        const int rl = (mr & 1) * 32 + l31;
        #pragma unroll
        for (int kk = 0; kk < 16; ++kk)
            qa[kk] = *(const bf16x8*)(qbfA + (((size_t)jbQ * 32 + kk * 2 + lhi) * 64 + rl) * 8);
    }
    // m-side constants: 2 scalar regs
    const float2 mv = qni[R0 + mr * 32 + l31];
    const float qn_m = mv.x, itv_m = mv.y;

    f32x16 o[4];
    #pragma unroll
    for (int ft = 0; ft < 4; ++ft)
        #pragma unroll
        for (int i = 0; i < 16; ++i) o[ft][i] = 0.f;
    float racc = 0.f;

    #pragma unroll 1
    for (int jt = 0; jt < NJT; ++jt) {
        const int jb = jbC0 + jt;
        const int C = jb * 64;

        // ---- S^T = K . Q^T  (D[j][m]: lane col = m = l31, regs = j) ----
        f32x16 s;
        #pragma unroll
        for (int i = 0; i < 16; ++i) s[i] = 0.f;
        #pragma unroll
        for (int kk = 0; kk < 16; ++kk) {
            bf16x8 kb = *(const bf16x8*)(qbfA + (((size_t)jb * 32 + kk * 2 + lhi) * 64 + jh * 32 + l31) * 8);
            s = __builtin_amdgcn_mfma_f32_32x32x16_bf16(kb, qa[kk], s, 0, 0, 0);
        }

        // ---- j-side constants: reg r -> j = jh*32 + (r&3) + 8*(r>>2) + 4*lhi ----
        float qnj[16], itj[16];
        #pragma unroll
        for (int rq = 0; rq < 4; ++rq) {
            int j0 = C + jh * 32 + rq * 8 + 4 * lhi;
            const float4* qp = (const float4*)(qni + j0);
            float4 q01 = qp[0], q23 = qp[1];
            qnj[rq * 4 + 0] = q01.x; itj[rq * 4 + 0] = q01.y;
            qnj[rq * 4 + 1] = q01.z; itj[rq * 4 + 1] = q01.w;
            qnj[rq * 4 + 2] = q23.x; itj[rq * 4 + 2] = q23.y;
            qnj[rq * 4 + 3] = q23.z; itj[rq * 4 + 3] = q23.w;
        }

        // ---- elementwise hyperbolic -> p (regs) ----
        float p[16];
        #pragma unroll
        for (int r = 0; r < 16; ++r) {
            float diff = fmaf(-2.0f, s[r], qn_m + qnj[r]);
            float z = fmaf(diff, itv_m * itj[r], 1.0f);
            z = fmaxf(z, 1.0f + EPSV) + EPSV;
            float y = z + sqrtf(fmaf(z, z, -1.0f));
            float pv = __builtin_amdgcn_exp2f(nrsc * __builtin_amdgcn_logf(y));
            racc += pv;
            p[r] = pv;
        }

        // ---- in-wave transpose to PV A-frag layout via shfl_xor(32) ----
        // A-frag (k-chunk kt): lane (m=l31,lhi) needs j = kt*16 + lhi*8 + e.
        float sh[16];
        #pragma unroll
        for (int r = 0; r < 16; ++r) sh[r] = __shfl_xor(p[r], 32, 64);
        bf16x8 af0, af1;
        #pragma unroll
        for (int e = 0; e < 4; ++e) {
            af0[e]     = (__bf16)(lhi ? sh[e + 4]  : p[e]);       // j kt0: lhi0 e<4: own j=e   | lhi1: j=8+e  from partner r4..7
            af0[e + 4] = (__bf16)(lhi ? p[e + 4]  : sh[e]);       // lhi0: j=4+e from partner r0..3 | lhi1: own j=12+e
            af1[e]     = (__bf16)(lhi ? sh[e + 12] : p[e + 8]);
            af1[e + 4] = (__bf16)(lhi ? p[e + 12] : sh[e + 8]);
        }

        // ---- publish A-frags: slot = mr*4 + (global kt = jh*2 + ktl) ----
        char* pxb = px + (jt & 1) * 16384;
        *(bf16x8*)(pxb + ((mr * 4 + jh * 2 + 0) * 1024) + lane * 16) = af0;
        *(bf16x8*)(pxb + ((mr * 4 + jh * 2 + 1) * 1024) + lane * 16) = af1;
        __syncthreads();

        // ---- O += P . V  (feats jh*128 + ft*32) ----
        #pragma unroll
        for (int kt = 0; kt < 4; ++kt) {
            bf16x8 pa = *(const bf16x8*)(pxb + ((mr * 4 + kt) * 1024) + lane * 16);
            #pragma unroll
            for (int ft = 0; ft < 4; ++ft) {
                bf16x8 vb = *(const bf16x8*)(qbfB +
                    (((size_t)jb * 8 + kt * 2 + lhi) * 256 + jh * 128 + ft * 32 + l31) * 8);
                o[ft] = __builtin_amdgcn_mfma_f32_32x32x16_bf16(pa, vb, o[ft], 0, 0, 0);
            }
        }
    }

    // ---- epilogue ----
    #pragma unroll
    for (int ft = 0; ft < 4; ++ft)
        #pragma unroll
        for (int r = 0; r < 16; ++r) {
            int row = R0 + mr * 32 + (r & 3) + 8 * (r >> 2) + 4 * lhi;
            int d = jh * 128 + ft * 32 + l31;
            atomicAdd(&Oacc[(size_t)row * DD + d], o[ft][r]);
        }
    racc += __shfl_xor(racc, 32, 64);
    if (lhi == 0) atomicAdd(&lacc[R0 + mr * 32 + l31], racc);
}

__global__ void norm_kernel(const float* __restrict__ Oacc, const float* __restrict__ lacc,
                            float* __restrict__ out) {
    int i = blockIdx.x * 256 + threadIdx.x;
    float4 v = ((const float4*)Oacc)[i];
    float inv = 1.0f / lacc[i >> 6];
    ((float4*)out)[i] = make_float4(v.x * inv, v.y * inv, v.z * inv, v.w * inv);
}

extern "C" void kernel_launch(void* const* d_in, const int* in_sizes, int n_in,
                              void* d_out, int out_size, void* d_ws, size_t ws_size,
                              hipStream_t stream) {
    (void)in_sizes; (void)n_in; (void)out_size; (void)ws_size;
    const float* q = (const float*)d_in[0];
    const float* cp = (const float*)d_in[1];
    float* out = (float*)d_out;
    float* ws = (float*)d_ws;
    float* Oacc = ws;
    float* lacc = ws + (size_t)NN * DD;
    float2* qni = (float2*)(lacc + NN);
    ushort* qbfA = (ushort*)(qni + NN);
    ushort* qbfB = qbfA + (size_t)NN * DD;

    prep_kernel<<<NN / 64, 256, 0, stream>>>(q, cp, qbfA, qbfB, qni, Oacc, lacc);
    flash_kernel<<<CSPLIT * (NN / BM), 512, 0, stream>>>(qbfA, qbfB, cp, qni, Oacc, lacc);
    norm_kernel<<<(NN * DD / 4) / 256, 256, 0, stream>>>(Oacc, lacc, out);
}

// Round 8
// 255.724 us; speedup vs baseline: 1.1318x; 1.1318x over previous
//
#include <hip/hip_runtime.h>
#include <math.h>

#define NN 8192
#define DD 256
#define EPSV 1e-6f
#define BM 32
#define BN 256
#define NJT (NN / BN)   // 32
#define TSTR 266

typedef __bf16 bf16x8 __attribute__((ext_vector_type(8)));
typedef float f32x16 __attribute__((ext_vector_type(16)));
typedef unsigned short ushort;
typedef unsigned int uint;

// ws layout: qni[NN] float2 | qbfA[NN*DD] bf16 | qbfB[NN*DD] bf16
// qbfA (A/B frag-major, 64-row blocks): elem(row,f) at ((rb*32 + f/8)*64 + row%64)*8 + f%8
// qbfB (PV B-frag-major): elem(j,f) at (((j>>4)*2 + ((j>>3)&1))*256 + f)*8 + (j&7)

__device__ inline ushort f2bf(float x) {
    uint u = __float_as_uint(x);
    u += 0x7fffu + ((u >> 16) & 1u);
    return (ushort)(u >> 16);
}

__global__ void prep_kernel(const float* __restrict__ q, const float* __restrict__ cp,
                            ushort* __restrict__ qbfA, ushort* __restrict__ qbfB,
                            float2* __restrict__ qni) {
    __shared__ ushort T[64 * TSTR];
    const int t = threadIdx.x;
    const int b = blockIdx.x;
    const int pr = t >> 2, fq = t & 3;
    const int row = b * 64 + pr;
    const float4* src = (const float4*)(q + (size_t)row * DD + fq * 64);
    ushort loc[64];
    float ss = 0.f;
    #pragma unroll
    for (int i = 0; i < 16; ++i) {
        float4 v = src[i];
        ushort b0 = f2bf(v.x), b1 = f2bf(v.y), b2 = f2bf(v.z), b3 = f2bf(v.w);
        loc[i * 4 + 0] = b0; loc[i * 4 + 1] = b1; loc[i * 4 + 2] = b2; loc[i * 4 + 3] = b3;
        float r0 = __uint_as_float((uint)b0 << 16), r1 = __uint_as_float((uint)b1 << 16);
        float r2 = __uint_as_float((uint)b2 << 16), r3 = __uint_as_float((uint)b3 << 16);
        ss += r0 * r0 + r1 * r1 + r2 * r2 + r3 * r3;
    }
    #pragma unroll
    for (int k = 0; k < 8; ++k)
        *(uint4*)(qbfA + (((size_t)b * 32 + fq * 8 + k) * 64 + pr) * 8) = *(uint4*)&loc[k * 8];
    #pragma unroll
    for (int k = 0; k < 32; ++k)
        *(ushort2*)&T[pr * TSTR + fq * 64 + k * 2] = *(ushort2*)&loc[k * 2];
    ss += __shfl_xor(ss, 1, 64);
    ss += __shfl_xor(ss, 2, 64);
    if (fq == 0) {
        float cc = fmaxf(cp[0], EPSV);
        float tt = fmaxf(1.0f - cc * ss, EPSV);
        qni[row] = make_float2(ss, sqrtf(2.0f * cc) / tt);
    }
    __syncthreads();
    #pragma unroll
    for (int pass = 0; pass < 4; ++pass) {
        int f = pass * 64 + (t >> 2);
        int quarter = t & 3;
        ushort tmp[16];
        #pragma unroll
        for (int i = 0; i < 16; ++i) tmp[i] = T[(quarter * 16 + i) * TSTR + f];
        *(uint4*)(qbfB + (((size_t)b * 8 + quarter * 2 + 0) * 256 + f) * 8) = *(uint4*)&tmp[0];
        *(uint4*)(qbfB + (((size_t)b * 8 + quarter * 2 + 1) * 256 + f) * 8) = *(uint4*)&tmp[8];
    }
}

__global__ __launch_bounds__(512, 2) void flash_kernel(
    const ushort* __restrict__ qbfA, const ushort* __restrict__ qbfB,
    const float* __restrict__ cp, const float2* __restrict__ qni,
    float* __restrict__ out) {
    __shared__ char px[32768];   // P-exchange: 2 buffers x 16 kchunk-slots x 1 KB
    __shared__ float lrow[32];

    const int tid = threadIdx.x;
    const int lane = tid & 63;
    const int w = tid >> 6;      // 0..7: S j-slice / PV feat-slice
    const int l31 = lane & 31;
    const int lhi = lane >> 5;
    const int bx = blockIdx.x;   // 256 blocks, each owns 32 rows fully
    const int R0 = bx * 32;

    if (tid < 32) lrow[tid] = 0.f;

    const float cc = fmaxf(cp[0], EPSV);
    const float nrsc = -rsqrtf(cc);

    // persistent Q B-fragments (rows R0 + l31, shared m-range for all waves)
    bf16x8 qa[16];
    {
        const int jbQ = bx >> 1;
        const int rl = (bx & 1) * 32 + l31;
        #pragma unroll
        for (int kk = 0; kk < 16; ++kk)
            qa[kk] = *(const bf16x8*)(qbfA + (((size_t)jbQ * 32 + kk * 2 + lhi) * 64 + rl) * 8);
    }
    const float2 mv = qni[R0 + l31];
    const float qn_m = mv.x, itv_m = mv.y;

    f32x16 o;
    #pragma unroll
    for (int i = 0; i < 16; ++i) o[i] = 0.f;
    float racc = 0.f;

    #pragma unroll 1
    for (int jt = 0; jt < NJT; ++jt) {
        const int J0 = jt * BN;

        // ---- S^T = K . Q^T : wave's j-slice = J0 + w*32 ----
        const int jbK = jt * 4 + (w >> 1);
        const int rlK = (w & 1) * 32 + l31;
        f32x16 s;
        #pragma unroll
        for (int i = 0; i < 16; ++i) s[i] = 0.f;
        #pragma unroll
        for (int kk = 0; kk < 16; ++kk) {
            bf16x8 kb = *(const bf16x8*)(qbfA + (((size_t)jbK * 32 + kk * 2 + lhi) * 64 + rlK) * 8);
            s = __builtin_amdgcn_mfma_f32_32x32x16_bf16(kb, qa[kk], s, 0, 0, 0);
        }

        // ---- j-side constants (broadcast float4 loads) ----
        float qnj[16], itj[16];
        #pragma unroll
        for (int rq = 0; rq < 4; ++rq) {
            int j0 = J0 + w * 32 + rq * 8 + 4 * lhi;
            const float4* qp = (const float4*)(qni + j0);
            float4 q01 = qp[0], q23 = qp[1];
            qnj[rq * 4 + 0] = q01.x; itj[rq * 4 + 0] = q01.y;
            qnj[rq * 4 + 1] = q01.z; itj[rq * 4 + 1] = q01.w;
            qnj[rq * 4 + 2] = q23.x; itj[rq * 4 + 2] = q23.y;
            qnj[rq * 4 + 3] = q23.z; itj[rq * 4 + 3] = q23.w;
        }

        // ---- elementwise hyperbolic -> p ----
        float p[16];
        #pragma unroll
        for (int r = 0; r < 16; ++r) {
            float diff = fmaf(-2.0f, s[r], qn_m + qnj[r]);
            float z = fmaf(diff, itv_m * itj[r], 1.0f);
            z = fmaxf(z, 1.0f + EPSV) + EPSV;
            float y = z + sqrtf(fmaf(z, z, -1.0f));
            float pv = __builtin_amdgcn_exp2f(nrsc * __builtin_amdgcn_logf(y));
            racc += pv;
            p[r] = pv;
        }

        // ---- in-wave transpose to PV A-frag layout (verified R7) ----
        float sh[16];
        #pragma unroll
        for (int r = 0; r < 16; ++r) sh[r] = __shfl_xor(p[r], 32, 64);
        bf16x8 af0, af1;
        #pragma unroll
        for (int e = 0; e < 4; ++e) {
            af0[e]     = (__bf16)(lhi ? sh[e + 4]  : p[e]);
            af0[e + 4] = (__bf16)(lhi ? p[e + 4]  : sh[e]);
            af1[e]     = (__bf16)(lhi ? sh[e + 12] : p[e + 8]);
            af1[e + 4] = (__bf16)(lhi ? p[e + 12] : sh[e + 8]);
        }

        // ---- publish: slots = wave's two kchunks ----
        char* pxb = px + (jt & 1) * 16384;
        *(bf16x8*)(pxb + (w * 2 + 0) * 1024 + lane * 16) = af0;
        *(bf16x8*)(pxb + (w * 2 + 1) * 1024 + lane * 16) = af1;
        __syncthreads();

        // ---- O += P . V : wave's feat-slice = w*32, k over all 16 kchunks ----
        #pragma unroll
        for (int kc = 0; kc < 16; ++kc) {
            bf16x8 pa = *(const bf16x8*)(pxb + kc * 1024 + lane * 16);
            bf16x8 vb = *(const bf16x8*)(qbfB +
                (((size_t)(jt * 16 + kc) * 2 + lhi) * 256 + w * 32 + l31) * 8);
            o = __builtin_amdgcn_mfma_f32_32x32x16_bf16(pa, vb, o, 0, 0, 0);
        }
    }

    // ---- epilogue: block-local softmax denom + direct normalized store ----
    racc += __shfl_xor(racc, 32, 64);
    if (lhi == 0) atomicAdd(&lrow[l31], racc);
    __syncthreads();
    #pragma unroll
    for (int r = 0; r < 16; ++r) {
        int row = (r & 3) + 8 * (r >> 2) + 4 * lhi;
        float inv = 1.0f / lrow[row];
        out[(size_t)(R0 + row) * DD + w * 32 + l31] = o[r] * inv;
    }
}

extern "C" void kernel_launch(void* const* d_in, const int* in_sizes, int n_in,
                              void* d_out, int out_size, void* d_ws, size_t ws_size,
                              hipStream_t stream) {
    (void)in_sizes; (void)n_in; (void)out_size; (void)ws_size;
    const float* q = (const float*)d_in[0];
    const float* cp = (const float*)d_in[1];
    float* out = (float*)d_out;
    float* ws = (float*)d_ws;
    float2* qni = (float2*)ws;
    ushort* qbfA = (ushort*)(qni + NN);
    ushort* qbfB = qbfA + (size_t)NN * DD;

    prep_kernel<<<NN / 64, 256, 0, stream>>>(q, cp, qbfA, qbfB, qni);
    flash_kernel<<<NN / BM, 512, 0, stream>>>(qbfA, qbfB, cp, qni, out);
}